// Round 6
// baseline (610.022 us; speedup 1.0000x reference)
//
#include <hip/hip_runtime.h>
#include <hip/hip_bf16.h>

#define V_ 32000
#define D_ 256
#define H_ 512
#define B_ 32
#define T_ 64
#define NSL 8   // column slices per batch
#define NB 4    // batches per GRU block; GRU grid = NSL * (B_/NB) = 64

typedef __attribute__((ext_vector_type(8))) __bf16 bf16x8;
typedef __attribute__((ext_vector_type(4))) float f32x4;
typedef _Float16 f16x2 __attribute__((ext_vector_type(2)));
typedef unsigned int u32t;
typedef unsigned long long u64t;

__device__ __forceinline__ u32t pack_h16(float a, float b) {
  union { _Float16 h; unsigned short u; } lo, hi;
  lo.h = (_Float16)a; hi.h = (_Float16)b;
  return (u32t)lo.u | ((u32t)hi.u << 16);
}

__device__ __forceinline__ float dot2(u32t w, u32t h, float acc) {
#if __has_builtin(__builtin_amdgcn_fdot2)
  return __builtin_amdgcn_fdot2(__builtin_bit_cast(f16x2, w),
                                __builtin_bit_cast(f16x2, h), acc, false);
#else
  f16x2 a = __builtin_bit_cast(f16x2, w);
  f16x2 b = __builtin_bit_cast(f16x2, h);
  return acc + (float)a.x * (float)b.x + (float)a.y * (float)b.y;
#endif
}

__device__ __forceinline__ void gld_lds16(const void* g, void* l) {
  __builtin_amdgcn_global_load_lds((const __attribute__((address_space(1))) void*)g,
                                   (__attribute__((address_space(3))) void*)l,
                                   16, 0, 0);
}

__device__ __forceinline__ u32t ld_rlx(const u32t* p) {
  return __hip_atomic_load(p, __ATOMIC_RELAXED, __HIP_MEMORY_SCOPE_AGENT);
}
__device__ __forceinline__ u64t ld_rlx64(const u64t* p) {
  return __hip_atomic_load(p, __ATOMIC_RELAXED, __HIP_MEMORY_SCOPE_AGENT);
}
__device__ __forceinline__ void st_rlx(u32t* p, u32t v) {
  __hip_atomic_store(p, v, __ATOMIC_RELAXED, __HIP_MEMORY_SCOPE_AGENT);
}

// ---------------- Wout [512][32000] f32 -> WoutT [32000][512] bf16 ----------------
__global__ __launch_bounds__(256) void k_transpose(const float* __restrict__ Wout,
                                                   __hip_bfloat16* __restrict__ WoutT) {
  __shared__ float tile[64][65];
  int v0 = blockIdx.x * 64;
  int h0 = blockIdx.y * 64;
  int tid = threadIdx.x;
#pragma unroll
  for (int i = 0; i < 16; ++i) {
    int idx = i * 256 + tid;
    int r = idx >> 6;
    int c = idx & 63;
    tile[r][c] = Wout[(size_t)(h0 + r) * V_ + v0 + c];
  }
  __syncthreads();
#pragma unroll
  for (int i = 0; i < 16; ++i) {
    int idx = i * 256 + tid;
    int rv = idx >> 6;
    int ch = idx & 63;
    WoutT[(size_t)(v0 + rv) * H_ + h0 + ch] = __float2bfloat16(tile[ch][rv]);
  }
}

// ---------------- weight packs (f16 pairs, per-thread register layouts) ----------
// Wg2 uint4 index: ((s*16 + it)*128 + cq)*4 + ks
//   col j = (cq<64) ? s*64+cq : 512 + s*64 + (cq-64);  k-span = ks*128 + it*8 .. +7
__global__ __launch_bounds__(256) void k_pack_g2(const float* __restrict__ Wg,
                                                 uint4* __restrict__ Wg2) {
  int gid = blockIdx.x * 256 + threadIdx.x;  // 0..65535
  int ks = gid & 3;
  int cq = (gid >> 2) & 127;
  int it = (gid >> 9) & 15;
  int s = gid >> 13;
  int j = (cq < 64) ? (s * 64 + cq) : (512 + s * 64 + (cq - 64));
  int k0 = ks * 128 + it * 8;
  uint4 v;
  v.x = pack_h16(Wg[(size_t)(256 + k0 + 0) * 1024 + j], Wg[(size_t)(256 + k0 + 1) * 1024 + j]);
  v.y = pack_h16(Wg[(size_t)(256 + k0 + 2) * 1024 + j], Wg[(size_t)(256 + k0 + 3) * 1024 + j]);
  v.z = pack_h16(Wg[(size_t)(256 + k0 + 4) * 1024 + j], Wg[(size_t)(256 + k0 + 5) * 1024 + j]);
  v.w = pack_h16(Wg[(size_t)(256 + k0 + 6) * 1024 + j], Wg[(size_t)(256 + k0 + 7) * 1024 + j]);
  Wg2[gid] = v;
}
// Wc2 uint4 index: ((s*8 + it)*64 + cq2)*8 + ks8 ; col jc = s*64+cq2; k-span ks8*64+it*8..+7
__global__ __launch_bounds__(256) void k_pack_c2(const float* __restrict__ Wc,
                                                 uint4* __restrict__ Wc2) {
  int gid = blockIdx.x * 256 + threadIdx.x;  // 0..32767
  int ks8 = gid & 7;
  int cq2 = (gid >> 3) & 63;
  int it = (gid >> 9) & 7;
  int s = gid >> 12;
  int jc = s * 64 + cq2;
  int k0 = ks8 * 64 + it * 8;
  uint4 v;
  v.x = pack_h16(Wc[(size_t)(256 + k0 + 0) * 512 + jc], Wc[(size_t)(256 + k0 + 1) * 512 + jc]);
  v.y = pack_h16(Wc[(size_t)(256 + k0 + 2) * 512 + jc], Wc[(size_t)(256 + k0 + 3) * 512 + jc]);
  v.z = pack_h16(Wc[(size_t)(256 + k0 + 4) * 512 + jc], Wc[(size_t)(256 + k0 + 5) * 512 + jc]);
  v.w = pack_h16(Wc[(size_t)(256 + k0 + 6) * 512 + jc], Wc[(size_t)(256 + k0 + 7) * 512 + jc]);
  Wc2[gid] = v;
}

// ---------------- x-projection (gate): pre_g[n][1024] = x_n @ Wg[:256] + bg ----------
__global__ __launch_bounds__(256) void k_precompute_g(const int* __restrict__ widx,
                                                      const float* __restrict__ embW,
                                                      const float* __restrict__ Wg,
                                                      const float* __restrict__ bg,
                                                      float* __restrict__ pre_g) {
  __shared__ __align__(16) float x2[D_][8];
  __shared__ int wid[8];
  int tid = threadIdx.x;
  int n0 = blockIdx.x * 8;
  if (tid < 8) wid[tid] = widx[n0 + tid];
  __syncthreads();
#pragma unroll
  for (int i = 0; i < 8; ++i)
    x2[tid][i] = embW[(size_t)wid[i] * D_ + tid];
  __syncthreads();

  int J = blockIdx.y * 256 + tid;  // 0..1023
  float bias = bg[J];
  float acc[8];
#pragma unroll
  for (int i = 0; i < 8; ++i) acc[i] = bias;
  for (int d = 0; d < D_; ++d) {
    float4 xa = *(const float4*)&x2[d][0];
    float4 xb = *(const float4*)&x2[d][4];
    float w = Wg[(size_t)d * 1024 + J];
    acc[0] = fmaf(xa.x, w, acc[0]); acc[1] = fmaf(xa.y, w, acc[1]);
    acc[2] = fmaf(xa.z, w, acc[2]); acc[3] = fmaf(xa.w, w, acc[3]);
    acc[4] = fmaf(xb.x, w, acc[4]); acc[5] = fmaf(xb.y, w, acc[5]);
    acc[6] = fmaf(xb.z, w, acc[6]); acc[7] = fmaf(xb.w, w, acc[7]);
  }
#pragma unroll
  for (int i = 0; i < 8; ++i)
    pre_g[(size_t)(n0 + i) * 1024 + J] = acc[i];
}

// ---------------- x-projection (cand): pre_c[n][512] = x_n @ Wc[:256] + bc ----------
__global__ __launch_bounds__(256) void k_precompute_c(const int* __restrict__ widx,
                                                      const float* __restrict__ embW,
                                                      const float* __restrict__ Wc,
                                                      const float* __restrict__ bc,
                                                      float* __restrict__ pre_c) {
  __shared__ __align__(16) float x2[D_][8];
  __shared__ int wid[8];
  int tid = threadIdx.x;
  int n0 = blockIdx.x * 8;
  if (tid < 8) wid[tid] = widx[n0 + tid];
  __syncthreads();
#pragma unroll
  for (int i = 0; i < 8; ++i)
    x2[tid][i] = embW[(size_t)wid[i] * D_ + tid];
  __syncthreads();

  int Jc = blockIdx.y * 256 + tid;  // 0..511
  float bias = bc[Jc];
  float acc[8];
#pragma unroll
  for (int i = 0; i < 8; ++i) acc[i] = bias;
  for (int d = 0; d < D_; ++d) {
    float4 xa = *(const float4*)&x2[d][0];
    float4 xb = *(const float4*)&x2[d][4];
    float w = Wc[(size_t)d * 512 + Jc];
    acc[0] = fmaf(xa.x, w, acc[0]); acc[1] = fmaf(xa.y, w, acc[1]);
    acc[2] = fmaf(xa.z, w, acc[2]); acc[3] = fmaf(xa.w, w, acc[3]);
    acc[4] = fmaf(xb.x, w, acc[4]); acc[5] = fmaf(xb.y, w, acc[5]);
    acc[6] = fmaf(xb.z, w, acc[6]); acc[7] = fmaf(xb.w, w, acc[7]);
  }
#pragma unroll
  for (int i = 0; i < 8; ++i)
    pre_c[(size_t)(n0 + i) * 512 + Jc] = acc[i];
}

// ---------------- GRU init: HB[b][wk] = packed f16 pair of enc; zero flags ----------
__global__ __launch_bounds__(256) void k_gru_init(const float* __restrict__ enc,
                                                  u32t* __restrict__ HB,
                                                  int* __restrict__ flags) {
  int gid = blockIdx.x * 256 + threadIdx.x;  // 0..8191
  int b = gid >> 8, wk = gid & 255;
  u32t v = pack_h16(enc[b * H_ + 2 * wk], enc[b * H_ + 2 * wk + 1]);
  st_rlx(&HB[gid], v);
#pragma unroll
  for (int i = 0; i < 4; ++i)
    st_rlx((u32t*)&flags[gid * 4 + i], 0);
}

// ---------------- GRU v6: 64 blocks = 8 slices x 8 batch-groups (4 batches/block) ----
// Weights depend only on slice s -> shared across the block's 4 batches (zero VGPR cost).
// Per phase: poll 4x8 flags with 32 lanes -> stage 4 KB (4 batches) -> 4 GEMV computes
// -> one vmcnt drain -> 4 flag stores. Exchange latency amortized 4x.
__global__ __launch_bounds__(512, 2) void k_gru6(const int* __restrict__ num_words,
                                                 const uint4* __restrict__ Wg2,
                                                 const uint4* __restrict__ Wc2,
                                                 const float* __restrict__ pre_g,
                                                 const float* __restrict__ pre_c,
                                                 u32t* __restrict__ RH,
                                                 u32t* __restrict__ HB,
                                                 int* __restrict__ flagR,
                                                 int* __restrict__ flagH,
                                                 u32t* __restrict__ A32) {
  __shared__ __align__(16) u32t h2_l[NB][256];
  __shared__ __align__(16) u32t rh2_l[NB][256];
  __shared__ float u_l[NB][64];
  int bid = blockIdx.x;
  int s = bid >> 3;   // slice 0..7
  int g = bid & 7;    // batch group 0..7 -> batches 4g..4g+3
  int tid = threadIdx.x;

  // phase-1 mapping: 128 gate cols x 4-way K-split
  int cq = tid >> 2, ks = tid & 3;
  int j1 = (cq < 64) ? (s * 64 + cq) : (512 + s * 64 + (cq - 64));
  // phase-2 mapping: 64 cand cols x 8-way K-split
  int cq2 = tid >> 3, ks8 = tid & 7;
  int jc = s * 64 + cq2;

  // ---- weights -> registers (pre-rotated for conflict-free LDS reads) ----
  uint4 wg[16];
#pragma unroll
  for (int i = 0; i < 16; ++i) {
    int ii = (i + ks) & 15;
    wg[i] = Wg2[(((size_t)s * 16 + ii) * 128 + cq) * 4 + ks];
  }
  uint4 wc[8];
#pragma unroll
  for (int i = 0; i < 8; ++i) {
    int ii = (i + ks8) & 7;
    wc[i] = Wc2[(((size_t)s * 8 + ii) * 64 + cq2) * 8 + ks8];
  }

  int nw[NB];
#pragma unroll
  for (int q = 0; q < NB; ++q) nw[q] = num_words[4 * g + q];

  const u64t* HB64 = (const u64t*)HB;
  const u64t* RH64 = (const u64t*)RH;
  // poll mapping (32 lanes): batch 4g+(tid>>3), slice tid&7
  int pb = 4 * g + (tid >> 3);
  int pflag_off = pb * 512 + (tid & 7) * 64;

  // stage mapping (256 lanes): batch-lane (q,l)
  int sq = tid >> 6, sl = tid & 63;  // valid when tid<256
  int sb = 4 * g + sq;

  bool writer1 = (ks == 0) && ((cq & 1) == 0) && (cq < 64);
  bool ulane = (ks == 0) && (cq >= 64);
  bool writer2 = (ks8 == 0) && ((cq2 & 1) == 0);

  for (int t = 0; t < T_; ++t) {
    // hoisted streamed loads
    float pg[NB], pc[NB];
#pragma unroll
    for (int q = 0; q < NB; ++q) {
      pg[q] = pre_g[((size_t)(4 * g + q) * T_ + t) * 1024 + j1];
      pc[q] = pre_c[((size_t)(4 * g + q) * T_ + t) * 512 + jc];
    }

    // ==== PHASE 1: gates ====
    if (tid < 32) {
      const u32t* fp = (const u32t*)&flagH[pflag_off];
      while ((int)ld_rlx(fp) < t) __builtin_amdgcn_s_sleep(1);
    }
    __syncthreads();
    if (tid < 256) {
      u64t v = ld_rlx64(&HB64[(size_t)sb * 128 + 2 * sl]);
      u64t v2 = ld_rlx64(&HB64[(size_t)sb * 128 + 2 * sl + 1]);
      *(u64t*)&h2_l[sq][4 * sl] = v;
      *(u64t*)&h2_l[sq][4 * sl + 2] = v2;
    }
    __syncthreads();

#pragma unroll
    for (int q = 0; q < NB; ++q) {
      int b = 4 * g + q;
      float a = 0.f;
      const uint4* h4 = (const uint4*)&h2_l[q][0];
#pragma unroll
      for (int i = 0; i < 16; ++i) {
        int ii = (i + ks) & 15;
        uint4 hv = h4[ks * 16 + ii];
        a = dot2(wg[i].x, hv.x, a);
        a = dot2(wg[i].y, hv.y, a);
        a = dot2(wg[i].z, hv.z, a);
        a = dot2(wg[i].w, hv.w, a);
      }
      a += __shfl_xor(a, 1);
      a += __shfl_xor(a, 2);
      float gate = 1.f / (1.f + __expf(-(a + pg[q])));
      if (cq < 64) {
        u32t hw = h2_l[q][(s * 64 + cq) >> 1];
        f16x2 hp = __builtin_bit_cast(f16x2, hw);
        float hh = (cq & 1) ? (float)hp.y : (float)hp.x;
        u32t mine = pack_h16(gate * hh, 0.f) & 0xffffu;
        u32t oth = (u32t)__shfl_xor((int)mine, 4);
        if (writer1)
          st_rlx(&RH[(size_t)b * 256 + s * 32 + (cq >> 1)], mine | (oth << 16));
      } else if (ulane) {
        u_l[q][cq - 64] = gate;
      }
    }

    asm volatile("s_waitcnt vmcnt(0)" ::: "memory");
    __syncthreads();
    if (tid < NB)
      st_rlx((u32t*)&flagR[(4 * g + tid) * 512 + s * 64], (u32t)(t + 1));

    // ==== PHASE 2: candidate + state update ====
    if (tid < 32) {
      const u32t* fp = (const u32t*)&flagR[pflag_off];
      while ((int)ld_rlx(fp) < t + 1) __builtin_amdgcn_s_sleep(1);
    }
    __syncthreads();
    if (tid < 256) {
      u64t v = ld_rlx64(&RH64[(size_t)sb * 128 + 2 * sl]);
      u64t v2 = ld_rlx64(&RH64[(size_t)sb * 128 + 2 * sl + 1]);
      *(u64t*)&rh2_l[sq][4 * sl] = v;
      *(u64t*)&rh2_l[sq][4 * sl + 2] = v2;
    }
    __syncthreads();

    u32t aw[NB];
#pragma unroll
    for (int q = 0; q < NB; ++q) {
      int b = 4 * g + q;
      float a2 = 0.f;
      const uint4* r4 = (const uint4*)&rh2_l[q][0];
#pragma unroll
      for (int i = 0; i < 8; ++i) {
        int ii = (i + ks8) & 7;
        uint4 rv = r4[ks8 * 8 + ii];
        a2 = dot2(wc[i].x, rv.x, a2);
        a2 = dot2(wc[i].y, rv.y, a2);
        a2 = dot2(wc[i].z, rv.z, a2);
        a2 = dot2(wc[i].w, rv.w, a2);
      }
      a2 += __shfl_xor(a2, 1);
      a2 += __shfl_xor(a2, 2);
      a2 += __shfl_xor(a2, 4);
      float cv = tanhf(a2 + pc[q]);
      float uu = u_l[q][cq2];
      u32t hw = h2_l[q][jc >> 1];
      f16x2 hp = __builtin_bit_cast(f16x2, hw);
      float hold = (cq2 & 1) ? (float)hp.y : (float)hp.x;
      float hn = uu * hold + (1.f - uu) * cv;
      bool live = t < nw[q];
      float hnext = live ? hn : hold;
      u32t mh = pack_h16(hnext, 0.f) & 0xffffu;
      u32t ma = (u32t)__hip_bfloat16_raw(__float2bfloat16(live ? hn : 0.f)).x;
      u32t oh = (u32t)__shfl_xor((int)mh, 8);
      u32t oa = (u32t)__shfl_xor((int)ma, 8);
      aw[q] = ma | (oa << 16);
      if (writer2)
        st_rlx(&HB[(size_t)b * 256 + s * 32 + (cq2 >> 1)], mh | (oh << 16));
    }

    asm volatile("s_waitcnt vmcnt(0)" ::: "memory");
    __syncthreads();
    if (tid < NB)
      st_rlx((u32t*)&flagH[(4 * g + tid) * 512 + s * 64], (u32t)(t + 1));
    if (writer2) {
#pragma unroll
      for (int q = 0; q < NB; ++q)
        A32[((size_t)(4 * g + q) * T_ + t) * 256 + s * 32 + (cq2 >> 1)] = aw[q];
    }
  }
}

// ---------------- projection: C[2048][32000] = A[2048][512] @ WoutT^T + bout -------
__global__ __launch_bounds__(256) void k_proj(const __hip_bfloat16* __restrict__ Ap,
                                              const __hip_bfloat16* __restrict__ BTp,
                                              const float* __restrict__ bout,
                                              float* __restrict__ C) {
  __shared__ char As[128 * 64 * 2];
  __shared__ char Bs[128 * 64 * 2];
  int tid = threadIdx.x;
  int lane = tid & 63;
  int wave = tid >> 6;
  int m0 = blockIdx.x * 128;
  int n0 = blockIdx.y * 128;
  int wm = wave >> 1, wn = wave & 1;
  f32x4 acc[4][4] = {};

  const char* Ab = (const char*)Ap;
  const char* Bb = (const char*)BTp;

  for (int ks = 0; ks < 8; ++ks) {
    int k0 = ks * 64;
    __syncthreads();
#pragma unroll
    for (int inst = 0; inst < 4; ++inst) {
      int o = inst * 4096 + wave * 1024;
      int ol = o + lane * 16;
      int r = ol >> 7;
      int cb = ol & 127;
      gld_lds16(Ab + ((size_t)(m0 + r) * 512 + k0) * 2 + cb, As + o);
      gld_lds16(Bb + ((size_t)(n0 + r) * 512 + k0) * 2 + cb, Bs + o);
    }
    __syncthreads();
#pragma unroll
    for (int kk = 0; kk < 64; kk += 32) {
      bf16x8 af[4], bfr[4];
      int cbyte = kk * 2 + ((lane >> 4) << 4);
#pragma unroll
      for (int mi = 0; mi < 4; ++mi) {
        int row = wm * 64 + mi * 16 + (lane & 15);
        af[mi] = *(const bf16x8*)(As + row * 128 + cbyte);
      }
#pragma unroll
      for (int ni = 0; ni < 4; ++ni) {
        int row = wn * 64 + ni * 16 + (lane & 15);
        bfr[ni] = *(const bf16x8*)(Bs + row * 128 + cbyte);
      }
#pragma unroll
      for (int mi = 0; mi < 4; ++mi)
#pragma unroll
        for (int ni = 0; ni < 4; ++ni)
          acc[mi][ni] = __builtin_amdgcn_mfma_f32_16x16x32_bf16(af[mi], bfr[ni], acc[mi][ni], 0, 0, 0);
    }
  }
#pragma unroll
  for (int ni = 0; ni < 4; ++ni) {
    int col = n0 + wn * 64 + ni * 16 + (lane & 15);
    float bb = bout[col];
#pragma unroll
    for (int mi = 0; mi < 4; ++mi) {
      int rbase = m0 + wm * 64 + mi * 16 + ((lane >> 4) << 2);
#pragma unroll
      for (int rr = 0; rr < 4; ++rr) {
        C[(size_t)(rbase + rr) * V_ + col] = acc[mi][ni][rr] + bb;
      }
    }
  }
}

extern "C" void kernel_launch(void* const* d_in, const int* in_sizes, int n_in,
                              void* d_out, int out_size, void* d_ws, size_t ws_size,
                              hipStream_t stream) {
  const int* widx = (const int*)d_in[0];
  const int* num_words = (const int*)d_in[1];
  const float* enc = (const float*)d_in[2];
  const float* embW = (const float*)d_in[3];
  const float* Wg = (const float*)d_in[4];
  const float* bg = (const float*)d_in[5];
  const float* Wc = (const float*)d_in[6];
  const float* bc = (const float*)d_in[7];
  const float* Wout = (const float*)d_in[8];
  const float* bout = (const float*)d_in[9];
  float* out = (float*)d_out;

  char* ws = (char*)d_ws;
  float* pre_g = (float*)(ws);                              // 8,388,608
  float* pre_c = (float*)(ws + 8388608);                    // 4,194,304
  __hip_bfloat16* A = (__hip_bfloat16*)(ws + 12582912);     // 2,097,152
  __hip_bfloat16* WoutT = (__hip_bfloat16*)(ws + 14680064); // 32,768,000
  uint4* Wg2 = (uint4*)(ws + 47448064);                     // 1,048,576
  uint4* Wc2 = (uint4*)(ws + 48496640);                     //   524,288
  u32t* RH = (u32t*)(ws + 49020928);                        //    32,768
  u32t* HB = (u32t*)(ws + 49053696);                        //    32,768
  int* flags = (int*)(ws + 49086464);                       //   131,072 (flagR | flagH)
  int* flagR = flags;                                       // 32*8 slices, 256B spaced
  int* flagH = flags + 16384;

  hipLaunchKernelGGL(k_pack_g2, dim3(256), dim3(256), 0, stream, Wg, Wg2);
  hipLaunchKernelGGL(k_pack_c2, dim3(128), dim3(256), 0, stream, Wc, Wc2);
  hipLaunchKernelGGL(k_transpose, dim3(500, 8), dim3(256), 0, stream, Wout, WoutT);
  hipLaunchKernelGGL(k_precompute_g, dim3(256, 4), dim3(256), 0, stream,
                     widx, embW, Wg, bg, pre_g);
  hipLaunchKernelGGL(k_precompute_c, dim3(256, 2), dim3(256), 0, stream,
                     widx, embW, Wc, bc, pre_c);
  hipLaunchKernelGGL(k_gru_init, dim3(32), dim3(256), 0, stream, enc, HB, flags);
  hipLaunchKernelGGL(k_gru6, dim3(64), dim3(512), 0, stream,
                     num_words, Wg2, Wc2, pre_g, pre_c, RH, HB, flagR, flagH, (u32t*)A);
  hipLaunchKernelGGL(k_proj, dim3(16, 250), dim3(256), 0, stream, A, WoutT, bout, out);
}

// Round 7
// 390.455 us; speedup vs baseline: 1.5623x; 1.5623x over previous
//
#include <hip/hip_runtime.h>
#include <hip/hip_bf16.h>

#define V_ 32000
#define D_ 256
#define H_ 512
#define B_ 32
#define T_ 64
#define NSL 8   // column slices per batch; GRU grid = 32*NSL = 256

typedef __attribute__((ext_vector_type(8))) __bf16 bf16x8;
typedef __attribute__((ext_vector_type(4))) float f32x4;
typedef _Float16 f16x2 __attribute__((ext_vector_type(2)));
typedef unsigned int u32t;
typedef unsigned short u16t;
typedef unsigned long long u64t;

__device__ __forceinline__ u32t pack_h16(float a, float b) {
  union { _Float16 h; unsigned short u; } lo, hi;
  lo.h = (_Float16)a; hi.h = (_Float16)b;
  return (u32t)lo.u | ((u32t)hi.u << 16);
}

__device__ __forceinline__ float f16u_to_f(u16t u) {
  union { _Float16 h; unsigned short u; } x;
  x.u = u;
  return (float)x.h;
}

__device__ __forceinline__ float dot2(u32t w, u32t h, float acc) {
#if __has_builtin(__builtin_amdgcn_fdot2)
  return __builtin_amdgcn_fdot2(__builtin_bit_cast(f16x2, w),
                                __builtin_bit_cast(f16x2, h), acc, false);
#else
  f16x2 a = __builtin_bit_cast(f16x2, w);
  f16x2 b = __builtin_bit_cast(f16x2, h);
  return acc + (float)a.x * (float)b.x + (float)a.y * (float)b.y;
#endif
}

__device__ __forceinline__ void gld_lds16(const void* g, void* l) {
  __builtin_amdgcn_global_load_lds((const __attribute__((address_space(1))) void*)g,
                                   (__attribute__((address_space(3))) void*)l,
                                   16, 0, 0);
}

__device__ __forceinline__ u32t ld_rlx(const u32t* p) {
  return __hip_atomic_load(p, __ATOMIC_RELAXED, __HIP_MEMORY_SCOPE_AGENT);
}
__device__ __forceinline__ void st_rlx(u32t* p, u32t v) {
  __hip_atomic_store(p, v, __ATOMIC_RELAXED, __HIP_MEMORY_SCOPE_AGENT);
}

// ---------------- Wout [512][32000] f32 -> WoutT [32000][512] bf16 ----------------
__global__ __launch_bounds__(256) void k_transpose(const float* __restrict__ Wout,
                                                   __hip_bfloat16* __restrict__ WoutT) {
  __shared__ float tile[64][65];
  int v0 = blockIdx.x * 64;
  int h0 = blockIdx.y * 64;
  int tid = threadIdx.x;
#pragma unroll
  for (int i = 0; i < 16; ++i) {
    int idx = i * 256 + tid;
    int r = idx >> 6;
    int c = idx & 63;
    tile[r][c] = Wout[(size_t)(h0 + r) * V_ + v0 + c];
  }
  __syncthreads();
#pragma unroll
  for (int i = 0; i < 16; ++i) {
    int idx = i * 256 + tid;
    int rv = idx >> 6;
    int ch = idx & 63;
    WoutT[(size_t)(v0 + rv) * H_ + h0 + ch] = __float2bfloat16(tile[ch][rv]);
  }
}

// ---------------- weight packs (f16 pairs, per-thread register layouts) ----------
// Wg2 uint4 index: ((s*16 + it)*128 + cq)*4 + ks
//   col j = (cq<64) ? s*64+cq : 512 + s*64 + (cq-64);  k-span = ks*128 + it*8 .. +7
__global__ __launch_bounds__(256) void k_pack_g2(const float* __restrict__ Wg,
                                                 uint4* __restrict__ Wg2) {
  int gid = blockIdx.x * 256 + threadIdx.x;  // 0..65535
  int ks = gid & 3;
  int cq = (gid >> 2) & 127;
  int it = (gid >> 9) & 15;
  int s = gid >> 13;
  int j = (cq < 64) ? (s * 64 + cq) : (512 + s * 64 + (cq - 64));
  int k0 = ks * 128 + it * 8;
  uint4 v;
  v.x = pack_h16(Wg[(size_t)(256 + k0 + 0) * 1024 + j], Wg[(size_t)(256 + k0 + 1) * 1024 + j]);
  v.y = pack_h16(Wg[(size_t)(256 + k0 + 2) * 1024 + j], Wg[(size_t)(256 + k0 + 3) * 1024 + j]);
  v.z = pack_h16(Wg[(size_t)(256 + k0 + 4) * 1024 + j], Wg[(size_t)(256 + k0 + 5) * 1024 + j]);
  v.w = pack_h16(Wg[(size_t)(256 + k0 + 6) * 1024 + j], Wg[(size_t)(256 + k0 + 7) * 1024 + j]);
  Wg2[gid] = v;
}
// Wc2 uint4 index: ((s*8 + it)*64 + cq2)*8 + ks8 ; col jc = s*64+cq2; k-span ks8*64+it*8..+7
__global__ __launch_bounds__(256) void k_pack_c2(const float* __restrict__ Wc,
                                                 uint4* __restrict__ Wc2) {
  int gid = blockIdx.x * 256 + threadIdx.x;  // 0..32767
  int ks8 = gid & 7;
  int cq2 = (gid >> 3) & 63;
  int it = (gid >> 9) & 7;
  int s = gid >> 12;
  int jc = s * 64 + cq2;
  int k0 = ks8 * 64 + it * 8;
  uint4 v;
  v.x = pack_h16(Wc[(size_t)(256 + k0 + 0) * 512 + jc], Wc[(size_t)(256 + k0 + 1) * 512 + jc]);
  v.y = pack_h16(Wc[(size_t)(256 + k0 + 2) * 512 + jc], Wc[(size_t)(256 + k0 + 3) * 512 + jc]);
  v.z = pack_h16(Wc[(size_t)(256 + k0 + 4) * 512 + jc], Wc[(size_t)(256 + k0 + 5) * 512 + jc]);
  v.w = pack_h16(Wc[(size_t)(256 + k0 + 6) * 512 + jc], Wc[(size_t)(256 + k0 + 7) * 512 + jc]);
  Wc2[gid] = v;
}

// ---------------- x-projection (gate): pre_g[n][1024] = x_n @ Wg[:256] + bg ----------
__global__ __launch_bounds__(256) void k_precompute_g(const int* __restrict__ widx,
                                                      const float* __restrict__ embW,
                                                      const float* __restrict__ Wg,
                                                      const float* __restrict__ bg,
                                                      float* __restrict__ pre_g) {
  __shared__ __align__(16) float x2[D_][8];
  __shared__ int wid[8];
  int tid = threadIdx.x;
  int n0 = blockIdx.x * 8;
  if (tid < 8) wid[tid] = widx[n0 + tid];
  __syncthreads();
#pragma unroll
  for (int i = 0; i < 8; ++i)
    x2[tid][i] = embW[(size_t)wid[i] * D_ + tid];
  __syncthreads();

  int J = blockIdx.y * 256 + tid;  // 0..1023
  float bias = bg[J];
  float acc[8];
#pragma unroll
  for (int i = 0; i < 8; ++i) acc[i] = bias;
  for (int d = 0; d < D_; ++d) {
    float4 xa = *(const float4*)&x2[d][0];
    float4 xb = *(const float4*)&x2[d][4];
    float w = Wg[(size_t)d * 1024 + J];
    acc[0] = fmaf(xa.x, w, acc[0]); acc[1] = fmaf(xa.y, w, acc[1]);
    acc[2] = fmaf(xa.z, w, acc[2]); acc[3] = fmaf(xa.w, w, acc[3]);
    acc[4] = fmaf(xb.x, w, acc[4]); acc[5] = fmaf(xb.y, w, acc[5]);
    acc[6] = fmaf(xb.z, w, acc[6]); acc[7] = fmaf(xb.w, w, acc[7]);
  }
#pragma unroll
  for (int i = 0; i < 8; ++i)
    pre_g[(size_t)(n0 + i) * 1024 + J] = acc[i];
}

// ---------------- x-projection (cand): pre_c[n][512] = x_n @ Wc[:256] + bc ----------
__global__ __launch_bounds__(256) void k_precompute_c(const int* __restrict__ widx,
                                                      const float* __restrict__ embW,
                                                      const float* __restrict__ Wc,
                                                      const float* __restrict__ bc,
                                                      float* __restrict__ pre_c) {
  __shared__ __align__(16) float x2[D_][8];
  __shared__ int wid[8];
  int tid = threadIdx.x;
  int n0 = blockIdx.x * 8;
  if (tid < 8) wid[tid] = widx[n0 + tid];
  __syncthreads();
#pragma unroll
  for (int i = 0; i < 8; ++i)
    x2[tid][i] = embW[(size_t)wid[i] * D_ + tid];
  __syncthreads();

  int Jc = blockIdx.y * 256 + tid;  // 0..511
  float bias = bc[Jc];
  float acc[8];
#pragma unroll
  for (int i = 0; i < 8; ++i) acc[i] = bias;
  for (int d = 0; d < D_; ++d) {
    float4 xa = *(const float4*)&x2[d][0];
    float4 xb = *(const float4*)&x2[d][4];
    float w = Wc[(size_t)d * 512 + Jc];
    acc[0] = fmaf(xa.x, w, acc[0]); acc[1] = fmaf(xa.y, w, acc[1]);
    acc[2] = fmaf(xa.z, w, acc[2]); acc[3] = fmaf(xa.w, w, acc[3]);
    acc[4] = fmaf(xb.x, w, acc[4]); acc[5] = fmaf(xb.y, w, acc[5]);
    acc[6] = fmaf(xb.z, w, acc[6]); acc[7] = fmaf(xb.w, w, acc[7]);
  }
#pragma unroll
  for (int i = 0; i < 8; ++i)
    pre_c[(size_t)(n0 + i) * 512 + Jc] = acc[i];
}

// ---------------- GRU init: tagged state buffers ----------------
// HBT[b][k] = {f16(enc[b][k]), tag=0}; RHT[b][k] = {0, tag=0xFFFF} (never matches).
__global__ __launch_bounds__(256) void k_gru_init(const float* __restrict__ enc,
                                                  u32t* __restrict__ HBT,
                                                  u32t* __restrict__ RHT) {
  int gid = blockIdx.x * 256 + threadIdx.x;  // 0..16383
  int b = gid >> 9, k = gid & 511;
  u32t hv = pack_h16(enc[b * H_ + k], 0.f) & 0xffffu;  // tag 0
  st_rlx(&HBT[gid], hv);
  st_rlx(&RHT[gid], 0xFFFF0000u);
}

// ---------------- GRU v7: tag-embedded payload exchange, no flags, no drains -------
// 256 blocks = 32 batches x 8 slices. Weights register-resident (as v5).
// Publish: u32 = {f16 value, u16 tag}; relaxed agent store, fire-and-forget.
// Consume: each of 512 lanes polls its own u32 until tag matches; one-way latency.
// Overwrite-before-consume is impossible: publishing step t+1 requires staging tags
// of step t, which requires every slice to have consumed step t's payload first.
__global__ __launch_bounds__(512, 2) void k_gru7(const int* __restrict__ num_words,
                                                 const uint4* __restrict__ Wg2,
                                                 const uint4* __restrict__ Wc2,
                                                 const float* __restrict__ pre_g,
                                                 const float* __restrict__ pre_c,
                                                 u32t* __restrict__ RHT,
                                                 u32t* __restrict__ HBT,
                                                 u32t* __restrict__ A32) {
  __shared__ __align__(16) u32t h2_l[256];
  __shared__ __align__(16) u32t rh2_l[256];
  __shared__ float u_l[64];
  int bid = blockIdx.x;
  int b = bid & 31;
  int s = bid >> 5;
  int tid = threadIdx.x;
  int nw = num_words[b];

  // phase-1 mapping: 128 gate cols x 4-way K-split
  int cq = tid >> 2, ks = tid & 3;
  int j1 = (cq < 64) ? (s * 64 + cq) : (512 + s * 64 + (cq - 64));
  // phase-2 mapping: 64 cand cols x 8-way K-split
  int cq2 = tid >> 3, ks8 = tid & 7;
  int jc = s * 64 + cq2;

  // ---- weights -> registers (pre-rotated for conflict-free LDS reads) ----
  uint4 wg[16];
#pragma unroll
  for (int i = 0; i < 16; ++i) {
    int ii = (i + ks) & 15;
    wg[i] = Wg2[(((size_t)s * 16 + ii) * 128 + cq) * 4 + ks];
  }
  uint4 wc[8];
#pragma unroll
  for (int i = 0; i < 8; ++i) {
    int ii = (i + ks8) & 7;
    wc[i] = Wc2[(((size_t)s * 8 + ii) * 64 + cq2) * 8 + ks8];
  }

  u32t* HBp = HBT + (size_t)b * 512;
  u32t* RHp = RHT + (size_t)b * 512;
  bool pub1 = (ks == 0) && (cq < 64);
  bool ulane = (ks == 0) && (cq >= 64);
  bool pub2 = (ks8 == 0);
  bool writer2 = pub2 && ((cq2 & 1) == 0);

  for (int t = 0; t < T_; ++t) {
    // hoisted streamed loads (L2-resident pre-projections)
    float pg = pre_g[((size_t)b * T_ + t) * 1024 + j1];
    float pc = pre_c[((size_t)b * T_ + t) * 512 + jc];

    // ---- stage h: poll tagged payload (tag == t) ----
    __syncthreads();  // protect h2_l/rh2_l/u_l from prior-step readers
    {
      u32t want = (u32t)t << 16;
      u32t v;
      do { v = ld_rlx(&HBp[tid]); } while ((v & 0xffff0000u) != want);
      ((volatile u16t*)h2_l)[tid] = (u16t)v;
    }
    __syncthreads();

    // ---- phase 1: gates ----
    float a = 0.f;
    const uint4* h4 = (const uint4*)h2_l;
#pragma unroll
    for (int i = 0; i < 16; ++i) {
      int ii = (i + ks) & 15;
      uint4 hv = h4[ks * 16 + ii];
      a = dot2(wg[i].x, hv.x, a);
      a = dot2(wg[i].y, hv.y, a);
      a = dot2(wg[i].z, hv.z, a);
      a = dot2(wg[i].w, hv.w, a);
    }
    a += __shfl_xor(a, 1);
    a += __shfl_xor(a, 2);
    float gate = 1.f / (1.f + __expf(-(a + pg)));
    if (cq < 64) {
      float hh = f16u_to_f(((const u16t*)h2_l)[s * 64 + cq]);
      if (pub1)
        st_rlx(&RHp[s * 64 + cq],
               (pack_h16(gate * hh, 0.f) & 0xffffu) | ((u32t)(t + 1) << 16));
    } else if (ulane) {
      u_l[cq - 64] = gate;
    }

    // ---- stage rh: poll tagged payload (tag == t+1) ----
    {
      u32t want = (u32t)(t + 1) << 16;
      u32t v;
      do { v = ld_rlx(&RHp[tid]); } while ((v & 0xffff0000u) != want);
      ((volatile u16t*)rh2_l)[tid] = (u16t)v;
    }
    __syncthreads();  // rh2_l + u_l ready for all

    // ---- phase 2: candidate + state update ----
    float a2 = 0.f;
    const uint4* r4 = (const uint4*)rh2_l;
#pragma unroll
    for (int i = 0; i < 8; ++i) {
      int ii = (i + ks8) & 7;
      uint4 rv = r4[ks8 * 8 + ii];
      a2 = dot2(wc[i].x, rv.x, a2);
      a2 = dot2(wc[i].y, rv.y, a2);
      a2 = dot2(wc[i].z, rv.z, a2);
      a2 = dot2(wc[i].w, rv.w, a2);
    }
    a2 += __shfl_xor(a2, 1);
    a2 += __shfl_xor(a2, 2);
    a2 += __shfl_xor(a2, 4);
    float cv = tanhf(a2 + pc);
    float uu = u_l[cq2];
    float hold = f16u_to_f(((const u16t*)h2_l)[jc]);
    float hn = uu * hold + (1.f - uu) * cv;
    bool live = t < nw;
    float hnext = live ? hn : hold;
    if (pub2)
      st_rlx(&HBp[s * 64 + cq2],
             (pack_h16(hnext, 0.f) & 0xffffu) | ((u32t)(t + 1) << 16));
    u32t ma = (u32t)__hip_bfloat16_raw(__float2bfloat16(live ? hn : 0.f)).x;
    u32t oa = (u32t)__shfl_xor((int)ma, 8);
    if (writer2)
      A32[(((size_t)b * T_ + t) * 512 + jc) >> 1] = ma | (oa << 16);
  }
}

// ---------------- projection: C[2048][32000] = A[2048][512] @ WoutT^T + bout -------
__global__ __launch_bounds__(256) void k_proj(const __hip_bfloat16* __restrict__ Ap,
                                              const __hip_bfloat16* __restrict__ BTp,
                                              const float* __restrict__ bout,
                                              float* __restrict__ C) {
  __shared__ char As[128 * 64 * 2];
  __shared__ char Bs[128 * 64 * 2];
  int tid = threadIdx.x;
  int lane = tid & 63;
  int wave = tid >> 6;
  int m0 = blockIdx.x * 128;
  int n0 = blockIdx.y * 128;
  int wm = wave >> 1, wn = wave & 1;
  f32x4 acc[4][4] = {};

  const char* Ab = (const char*)Ap;
  const char* Bb = (const char*)BTp;

  for (int ks = 0; ks < 8; ++ks) {
    int k0 = ks * 64;
    __syncthreads();
#pragma unroll
    for (int inst = 0; inst < 4; ++inst) {
      int o = inst * 4096 + wave * 1024;
      int ol = o + lane * 16;
      int r = ol >> 7;
      int cb = ol & 127;
      gld_lds16(Ab + ((size_t)(m0 + r) * 512 + k0) * 2 + cb, As + o);
      gld_lds16(Bb + ((size_t)(n0 + r) * 512 + k0) * 2 + cb, Bs + o);
    }
    __syncthreads();
#pragma unroll
    for (int kk = 0; kk < 64; kk += 32) {
      bf16x8 af[4], bfr[4];
      int cbyte = kk * 2 + ((lane >> 4) << 4);
#pragma unroll
      for (int mi = 0; mi < 4; ++mi) {
        int row = wm * 64 + mi * 16 + (lane & 15);
        af[mi] = *(const bf16x8*)(As + row * 128 + cbyte);
      }
#pragma unroll
      for (int ni = 0; ni < 4; ++ni) {
        int row = wn * 64 + ni * 16 + (lane & 15);
        bfr[ni] = *(const bf16x8*)(Bs + row * 128 + cbyte);
      }
#pragma unroll
      for (int mi = 0; mi < 4; ++mi)
#pragma unroll
        for (int ni = 0; ni < 4; ++ni)
          acc[mi][ni] = __builtin_amdgcn_mfma_f32_16x16x32_bf16(af[mi], bfr[ni], acc[mi][ni], 0, 0, 0);
    }
  }
#pragma unroll
  for (int ni = 0; ni < 4; ++ni) {
    int col = n0 + wn * 64 + ni * 16 + (lane & 15);
    float bb = bout[col];
#pragma unroll
    for (int mi = 0; mi < 4; ++mi) {
      int rbase = m0 + wm * 64 + mi * 16 + ((lane >> 4) << 2);
#pragma unroll
      for (int rr = 0; rr < 4; ++rr) {
        C[(size_t)(rbase + rr) * V_ + col] = acc[mi][ni][rr] + bb;
      }
    }
  }
}

extern "C" void kernel_launch(void* const* d_in, const int* in_sizes, int n_in,
                              void* d_out, int out_size, void* d_ws, size_t ws_size,
                              hipStream_t stream) {
  const int* widx = (const int*)d_in[0];
  const int* num_words = (const int*)d_in[1];
  const float* enc = (const float*)d_in[2];
  const float* embW = (const float*)d_in[3];
  const float* Wg = (const float*)d_in[4];
  const float* bg = (const float*)d_in[5];
  const float* Wc = (const float*)d_in[6];
  const float* bc = (const float*)d_in[7];
  const float* Wout = (const float*)d_in[8];
  const float* bout = (const float*)d_in[9];
  float* out = (float*)d_out;

  char* ws = (char*)d_ws;
  float* pre_g = (float*)(ws);                              // 8,388,608
  float* pre_c = (float*)(ws + 8388608);                    // 4,194,304
  __hip_bfloat16* A = (__hip_bfloat16*)(ws + 12582912);     // 2,097,152
  __hip_bfloat16* WoutT = (__hip_bfloat16*)(ws + 14680064); // 32,768,000
  uint4* Wg2 = (uint4*)(ws + 47448064);                     // 1,048,576
  uint4* Wc2 = (uint4*)(ws + 48496640);                     //   524,288
  u32t* RHT = (u32t*)(ws + 49020928);                       //    65,536 (tagged)
  u32t* HBT = (u32t*)(ws + 49086464);                       //    65,536 (tagged)

  hipLaunchKernelGGL(k_pack_g2, dim3(256), dim3(256), 0, stream, Wg, Wg2);
  hipLaunchKernelGGL(k_pack_c2, dim3(128), dim3(256), 0, stream, Wc, Wc2);
  hipLaunchKernelGGL(k_transpose, dim3(500, 8), dim3(256), 0, stream, Wout, WoutT);
  hipLaunchKernelGGL(k_precompute_g, dim3(256, 4), dim3(256), 0, stream,
                     widx, embW, Wg, bg, pre_g);
  hipLaunchKernelGGL(k_precompute_c, dim3(256, 2), dim3(256), 0, stream,
                     widx, embW, Wc, bc, pre_c);
  hipLaunchKernelGGL(k_gru_init, dim3(64), dim3(256), 0, stream, enc, HBT, RHT);
  hipLaunchKernelGGL(k_gru7, dim3(32 * NSL), dim3(512), 0, stream,
                     num_words, Wg2, Wc2, pre_g, pre_c, RHT, HBT, (u32t*)A);
  hipLaunchKernelGGL(k_proj, dim3(16, 250), dim3(256), 0, stream, A, WoutT, bout, out);
}